// Round 2
// baseline (1968.011 us; speedup 1.0000x reference)
//
#include <hip/hip_runtime.h>
#include <hip/hip_bf16.h>
#include <math.h>

constexpr int NN = 1024;          // nodes
constexpr int NB = 32;            // batch
constexpr int ROWS = NB * NN;     // 32768 rows for BN
constexpr int NSLICE = 8;         // colsum partial slices (deterministic)

// ---------------------------------------------------------------------------
// Laplacian: computed IN PLACE over A (harness restores inputs every launch).
// Pass 1: W = A / (dist + 1e-3); partial colsums S[slice][b,j] (no atomics)
// Pass 2: d = 1/sqrt(sum S); L = -0.5*delta_ij - 0.5 * d_i * W * d_j
// ---------------------------------------------------------------------------

__global__ __launch_bounds__(256) void colsum_w(float* __restrict__ A,
                                                const float* __restrict__ x,
                                                float* __restrict__ S) {
  const int b = blockIdx.z;
  const int j = blockIdx.x * 256 + threadIdx.x;   // column handled by thread
  const int slice = blockIdx.y;
  const int ibase = slice * 128;                  // i-slice
  __shared__ float xs[128 * 3];
  for (int idx = threadIdx.x; idx < 384; idx += 256)
    xs[idx] = x[(size_t)(b * NN + ibase) * 3 + idx];
  const float xj0 = x[(size_t)(b * NN + j) * 3 + 0];
  const float xj1 = x[(size_t)(b * NN + j) * 3 + 1];
  const float xj2 = x[(size_t)(b * NN + j) * 3 + 2];
  __syncthreads();
  float s = 0.f;
  size_t off = ((size_t)b << 20) + (size_t)ibase * NN + j;
  for (int ii = 0; ii < 128; ++ii, off += NN) {
    float a = A[off];
    float dx = xj0 - xs[ii * 3 + 0];
    float dy = xj1 - xs[ii * 3 + 1];
    float dz = xj2 - xs[ii * 3 + 2];
    float dist = sqrtf(dx * dx + dy * dy + dz * dz);
    float w = a / (dist + 0.001f);
    A[off] = w;                                   // W in place (own element)
    s += w;
  }
  S[(size_t)slice * ROWS + b * NN + j] = s;       // written exactly once
}

__global__ __launch_bounds__(256) void d_kernel(const float* __restrict__ S,
                                                float* __restrict__ D) {
  int i = blockIdx.x * 256 + threadIdx.x;
  if (i < ROWS) {
    float s = 0.f;
#pragma unroll
    for (int p = 0; p < NSLICE; ++p) s += S[(size_t)p * ROWS + i];
    D[i] = 1.f / sqrtf(s);
  }
}

__global__ __launch_bounds__(256) void scale_L(float* __restrict__ A,
                                               const float* __restrict__ D) {
  const long total4 = (long)NB * NN * NN / 4;
  for (long idx = (long)blockIdx.x * 256 + threadIdx.x; idx < total4;
       idx += (long)gridDim.x * 256) {
    long base = idx * 4;
    int j0 = (int)(base & (NN - 1));
    int i = (int)((base >> 10) & (NN - 1));
    int b = (int)(base >> 20);
    float4 w = reinterpret_cast<float4*>(A)[idx];
    float di = D[b * NN + i];
    float4 dj = *reinterpret_cast<const float4*>(&D[b * NN + j0]);
    float4 l;
    l.x = -0.5f * di * dj.x * w.x;
    l.y = -0.5f * di * dj.y * w.y;
    l.z = -0.5f * di * dj.z * w.z;
    l.w = -0.5f * di * dj.w * w.w;
    int dd = i - j0;
    if (dd == 0) l.x -= 0.5f;
    else if (dd == 1) l.y -= 0.5f;
    else if (dd == 2) l.z -= 0.5f;
    else if (dd == 3) l.w -= 0.5f;
    reinterpret_cast<float4*>(A)[idx] = l;
  }
}

// ---------------------------------------------------------------------------
// acc = h @ W0  (the k=0 term, overwrite).  RB=64 rows per block.
// ---------------------------------------------------------------------------
template <int F, int G>
__global__ __launch_bounds__(256) void acc0_gemm(const float* __restrict__ h,
                                                 const float* __restrict__ W0,
                                                 float* __restrict__ acc) {
  constexpr int RB = 64;
  constexpr int TGN = G / 16;
  __shared__ float Hs[RB][F + 1];
  __shared__ float Ws[F][G];
  const int tid = threadIdx.x;
  const size_t row0 = (size_t)blockIdx.x * RB;
  for (int idx = tid; idx < RB * F; idx += 256)
    Hs[idx / F][idx % F] = h[row0 * F + idx];
  for (int idx = tid; idx < F * G; idx += 256)
    Ws[idx / G][idx % G] = W0[idx];
  __syncthreads();
  const int tx = tid % 16, ty = tid / 16;
  float o[4][TGN];
#pragma unroll
  for (int r = 0; r < 4; ++r)
#pragma unroll
    for (int c = 0; c < TGN; ++c) o[r][c] = 0.f;
#pragma unroll 4
  for (int f = 0; f < F; ++f) {
    float a[4];
#pragma unroll
    for (int r = 0; r < 4; ++r) a[r] = Hs[ty * 4 + r][f];
#pragma unroll
    for (int c = 0; c < TGN; ++c) {
      float w = Ws[f][tx * TGN + c];
#pragma unroll
      for (int r = 0; r < 4; ++r) o[r][c] = fmaf(a[r], w, o[r][c]);
    }
  }
#pragma unroll
  for (int r = 0; r < 4; ++r) {
    size_t base = (row0 + ty * 4 + r) * G + tx * TGN;
#pragma unroll
    for (int c = 0; c < TGN; ++c) acc[base + c] = o[r][c];
  }
}

// ---------------------------------------------------------------------------
// Layer-1 recursion (F=3). Block = 256 thr (4 waves), 16 rows (4 per wave).
// Stages full per-batch Tprev (1024x3 = 12KB) in LDS; L rows streamed
// coalesced; fused epilogue acc += Tk @ Wk (G=32).
// ---------------------------------------------------------------------------
__global__ __launch_bounds__(256) void cheb_l1(
    const float* __restrict__ Lg, const float* __restrict__ Tprev,
    const float* __restrict__ Tpp, float* __restrict__ Tk,
    const float* __restrict__ Wk, float* __restrict__ acc, float alpha,
    float beta) {
  __shared__ float Ts[NN * 3];        // 12 KB
  __shared__ float tkv[16][4];
  const int b = blockIdx.y;
  const int i0 = blockIdx.x * 16;
  const int tid = threadIdx.x;
  // stage Tprev[b] (3072 floats, float4 coalesced)
  const float* tpb = &Tprev[(size_t)b * NN * 3];
  for (int idx = tid; idx < 768; idx += 256)
    *reinterpret_cast<float4*>(&Ts[idx * 4]) =
        *reinterpret_cast<const float4*>(&tpb[idx * 4]);
  __syncthreads();
  const int wv = tid >> 6, ln = tid & 63;
#pragma unroll
  for (int r = 0; r < 4; ++r) {
    const int i = i0 + wv * 4 + r;
    const float* Lrow = &Lg[((size_t)b << 20) + (size_t)i * NN];
    float a0 = 0.f, a1 = 0.f, a2 = 0.f;
#pragma unroll
    for (int c = 0; c < 16; ++c) {
      int j = c * 64 + ln;
      float w = Lrow[j];
      a0 = fmaf(w, Ts[j * 3 + 0], a0);
      a1 = fmaf(w, Ts[j * 3 + 1], a1);
      a2 = fmaf(w, Ts[j * 3 + 2], a2);
    }
#pragma unroll
    for (int off = 32; off; off >>= 1) {
      a0 += __shfl_down(a0, off, 64);
      a1 += __shfl_down(a1, off, 64);
      a2 += __shfl_down(a2, off, 64);
    }
    if (ln == 0) {
      const size_t rbase = (size_t)(b * NN + i) * 3;
      float t0 = alpha * a0, t1 = alpha * a1, t2 = alpha * a2;
      if (beta != 0.f) {
        t0 = fmaf(beta, Tpp[rbase + 0], t0);
        t1 = fmaf(beta, Tpp[rbase + 1], t1);
        t2 = fmaf(beta, Tpp[rbase + 2], t2);
      }
      Tk[rbase + 0] = t0;
      Tk[rbase + 1] = t1;
      Tk[rbase + 2] = t2;
      tkv[wv * 4 + r][0] = t0;
      tkv[wv * 4 + r][1] = t1;
      tkv[wv * 4 + r][2] = t2;
    }
  }
  __syncthreads();
  // epilogue: acc[16 rows][32 cols] += tkv @ Wk(3x32)
  for (int idx = tid; idx < 16 * 32; idx += 256) {
    int rr = idx >> 5, cc = idx & 31;
    float v = tkv[rr][0] * Wk[cc] + tkv[rr][1] * Wk[32 + cc] +
              tkv[rr][2] * Wk[64 + cc];
    acc[(size_t)(b * NN + i0 + rr) * 32 + cc] += v;
  }
}

// ---------------------------------------------------------------------------
// Main recursion GEMM (F=32 / 64):  Tk = alpha * L @ Tprev + beta * Tpp
// Fused epilogue: acc += Tk_tile @ Wk   (block owns its rows exclusively)
// ---------------------------------------------------------------------------
template <int BM, int F, int G>
__global__ __launch_bounds__(256) void cheb_gemm(
    const float* __restrict__ Lg, const float* __restrict__ Tprev,
    const float* __restrict__ Tpp, float* __restrict__ Tk,
    const float* __restrict__ Wk, float* __restrict__ acc, float alpha,
    float beta) {
  constexpr int BK = 32;
  constexpr int TM = 4, TN = 4;
  constexpr int NTX = F / TN;
  constexpr int NTY = BM / TM;
  static_assert(NTX * NTY == 256, "tile mismatch");
  constexpr int TGN = G / NTX;

  __shared__ float As[BM][BK + 1];   // L tile, row-major, padded
  __shared__ float Bs[BK][F];        // Tprev tile
  __shared__ float Ws[F][G];         // weight slice
  __shared__ float Ts[BM][F + 1];    // Tk tile for epilogue

  const int tid = threadIdx.x;
  const int tx = tid % NTX, ty = tid / NTX;
  const int b = blockIdx.y;
  const int i0 = blockIdx.x * BM;

  constexpr int W_ITERS = (F * G / 4) / 256;
#pragma unroll
  for (int it = 0; it < W_ITERS; ++it) {
    int idx = tid + it * 256;
    int r = idx / (G / 4), c4 = idx % (G / 4);
    float4 v = *reinterpret_cast<const float4*>(&Wk[r * G + c4 * 4]);
    *reinterpret_cast<float4*>(&Ws[r][c4 * 4]) = v;
  }

  float accT[TM][TN];
#pragma unroll
  for (int r = 0; r < TM; ++r)
#pragma unroll
    for (int c = 0; c < TN; ++c) accT[r][c] = 0.f;

  const size_t Lbase = ((size_t)b << 20);
  constexpr int A_ITERS = (BM * (BK / 4)) / 256;
  constexpr int B_ITERS = (BK * (F / 4)) / 256 > 0 ? (BK * (F / 4)) / 256 : 1;

  for (int k0 = 0; k0 < NN; k0 += BK) {
#pragma unroll
    for (int it = 0; it < A_ITERS; ++it) {
      int idx = tid + it * 256;
      int m = idx >> 3, k4 = idx & 7;
      float4 v = *reinterpret_cast<const float4*>(
          &Lg[Lbase + (size_t)(i0 + m) * NN + k0 + k4 * 4]);
      As[m][k4 * 4 + 0] = v.x;
      As[m][k4 * 4 + 1] = v.y;
      As[m][k4 * 4 + 2] = v.z;
      As[m][k4 * 4 + 3] = v.w;
    }
#pragma unroll
    for (int it = 0; it < B_ITERS; ++it) {
      int idx = tid + it * 256;
      int kr = idx / (F / 4), c4 = idx % (F / 4);
      float4 v = *reinterpret_cast<const float4*>(
          &Tprev[(size_t)(b * NN + k0 + kr) * F + c4 * 4]);
      *reinterpret_cast<float4*>(&Bs[kr][c4 * 4]) = v;
    }
    __syncthreads();
#pragma unroll
    for (int kk = 0; kk < BK; ++kk) {
      float a[TM];
#pragma unroll
      for (int r = 0; r < TM; ++r) a[r] = As[ty * TM + r][kk];
      float4 bv = *reinterpret_cast<const float4*>(&Bs[kk][tx * TN]);
      float bb[4] = {bv.x, bv.y, bv.z, bv.w};
#pragma unroll
      for (int r = 0; r < TM; ++r)
#pragma unroll
        for (int c = 0; c < TN; ++c)
          accT[r][c] = fmaf(a[r], bb[c], accT[r][c]);
    }
    __syncthreads();
  }

  // Tk = alpha*accT + beta*Tpp : write to global + stash in LDS for epilogue
  const bool hasB = (beta != 0.f);
#pragma unroll
  for (int r = 0; r < TM; ++r) {
    int row = i0 + ty * TM + r;
    size_t gidx = (size_t)(b * NN + row) * F + tx * TN;
    float t0 = alpha * accT[r][0], t1 = alpha * accT[r][1];
    float t2 = alpha * accT[r][2], t3 = alpha * accT[r][3];
    if (hasB) {
      float4 p = *reinterpret_cast<const float4*>(&Tpp[gidx]);
      t0 = fmaf(beta, p.x, t0);
      t1 = fmaf(beta, p.y, t1);
      t2 = fmaf(beta, p.z, t2);
      t3 = fmaf(beta, p.w, t3);
    }
    float4 tv = {t0, t1, t2, t3};
    *reinterpret_cast<float4*>(&Tk[gidx]) = tv;
    Ts[ty * TM + r][tx * TN + 0] = t0;
    Ts[ty * TM + r][tx * TN + 1] = t1;
    Ts[ty * TM + r][tx * TN + 2] = t2;
    Ts[ty * TM + r][tx * TN + 3] = t3;
  }
  __syncthreads();

  float oacc[TM][TGN];
#pragma unroll
  for (int r = 0; r < TM; ++r)
#pragma unroll
    for (int c = 0; c < TGN; ++c) oacc[r][c] = 0.f;
#pragma unroll 8
  for (int f = 0; f < F; ++f) {
    float a[TM];
#pragma unroll
    for (int r = 0; r < TM; ++r) a[r] = Ts[ty * TM + r][f];
#pragma unroll
    for (int c = 0; c < TGN; ++c) {
      float w = Ws[f][tx * TGN + c];
#pragma unroll
      for (int r = 0; r < TM; ++r) oacc[r][c] = fmaf(a[r], w, oacc[r][c]);
    }
  }
#pragma unroll
  for (int r = 0; r < TM; ++r) {
    int row = i0 + ty * TM + r;
    size_t base = (size_t)(b * NN + row) * G + tx * TGN;
#pragma unroll
    for (int c = 0; c < TGN; ++c) acc[base + c] += oacc[r][c];
  }
}

// ---------------------------------------------------------------------------
// BatchNorm (train, biased var) + ELU
// ---------------------------------------------------------------------------
constexpr int BN_BLOCKS = 256;

template <int C>
__global__ __launch_bounds__(256) void bn_part(const float* __restrict__ acc,
                                               double* __restrict__ part) {
  constexpr int GR = 256 / C;
  const int tid = threadIdx.x;
  const int c = tid % C;
  const int g = tid / C;
  double s = 0.0, s2 = 0.0;
  for (int r = blockIdx.x * GR + g; r < ROWS; r += BN_BLOCKS * GR) {
    double v = (double)acc[(size_t)r * C + c];
    s += v;
    s2 += v * v;
  }
  __shared__ double Ls[256], Ls2[256];
  Ls[tid] = s;
  Ls2[tid] = s2;
  __syncthreads();
  for (int str = 128; str >= C; str >>= 1) {
    if (tid < str) {
      Ls[tid] += Ls[tid + str];
      Ls2[tid] += Ls2[tid + str];
    }
    __syncthreads();
  }
  if (tid < C) {
    part[(size_t)blockIdx.x * 2 * C + tid] = Ls[tid];
    part[(size_t)blockIdx.x * 2 * C + C + tid] = Ls2[tid];
  }
}

template <int C>
__global__ void bn_final(const double* __restrict__ part,
                         const float* __restrict__ g,
                         const float* __restrict__ be,
                         float* __restrict__ sc) {
  int t = threadIdx.x;
  if (t < C) {
    double s = 0.0, s2 = 0.0;
    for (int b = 0; b < BN_BLOCKS; ++b) {
      s += part[(size_t)b * 2 * C + t];
      s2 += part[(size_t)b * 2 * C + C + t];
    }
    double mu = s / ROWS;
    double var = s2 / ROWS - mu * mu;
    float scale = g[t] / sqrtf((float)var + 1e-5f);
    sc[t] = scale;
    sc[C + t] = be[t] - (float)mu * scale;
  }
}

template <int C>
__global__ __launch_bounds__(256) void bn_apply_elu(
    const float* __restrict__ acc, const float* __restrict__ sc,
    float* __restrict__ h) {
  const long total4 = (long)ROWS * C / 4;
  for (long idx = (long)blockIdx.x * 256 + threadIdx.x; idx < total4;
       idx += (long)gridDim.x * 256) {
    long base = idx * 4;
    int c0 = (int)(base % C);
    float4 v = reinterpret_cast<const float4*>(acc)[idx];
    float t0 = fmaf(v.x, sc[c0 + 0], sc[C + c0 + 0]);
    float t1 = fmaf(v.y, sc[c0 + 1], sc[C + c0 + 1]);
    float t2 = fmaf(v.z, sc[c0 + 2], sc[C + c0 + 2]);
    float t3 = fmaf(v.w, sc[c0 + 3], sc[C + c0 + 3]);
    float4 o;
    o.x = t0 > 0.f ? t0 : expm1f(t0);
    o.y = t1 > 0.f ? t1 : expm1f(t1);
    o.z = t2 > 0.f ? t2 : expm1f(t2);
    o.w = t3 > 0.f ? t3 : expm1f(t3);
    reinterpret_cast<float4*>(h)[idx] = o;
  }
}

// ---------------------------------------------------------------------------
// Final: mean over nodes, dot with Wfc, + bfc
// ---------------------------------------------------------------------------
__global__ __launch_bounds__(256) void final_k(const float* __restrict__ h,
                                               const float* __restrict__ Wfc,
                                               const float* __restrict__ bfc,
                                               float* __restrict__ out) {
  const int b = blockIdx.x;
  const int tid = threadIdx.x;
  const int c = tid % 64;
  const int g = tid / 64;
  float s = 0.f;
  for (int r = g; r < NN; r += 4) s += h[(size_t)(b * NN + r) * 64 + c];
  __shared__ float red[256];
  red[tid] = s;
  __syncthreads();
  if (tid < 128) red[tid] += red[tid + 128];
  __syncthreads();
  if (tid < 64) {
    float pooled = (red[tid] + red[tid + 64]) * (1.0f / 1024.0f);
    float v = pooled * Wfc[tid];
#pragma unroll
    for (int off = 32; off; off >>= 1) v += __shfl_down(v, off, 64);
    if (tid == 0) out[b] = v + bfc[0];
  }
}

// ---------------------------------------------------------------------------
extern "C" void kernel_launch(void* const* d_in, const int* in_sizes, int n_in,
                              void* d_out, int out_size, void* d_ws,
                              size_t ws_size, hipStream_t stream) {
  const float* x = (const float*)d_in[0];
  float* A = (float*)d_in[1];  // overwritten in place with L (inputs restored per launch)
  const float* W1 = (const float*)d_in[2];
  const float* g1 = (const float*)d_in[4];
  const float* be1 = (const float*)d_in[5];
  const float* W2 = (const float*)d_in[6];
  const float* g2 = (const float*)d_in[8];
  const float* be2 = (const float*)d_in[9];
  const float* W3 = (const float*)d_in[10];
  const float* g3 = (const float*)d_in[12];
  const float* be3 = (const float*)d_in[13];
  const float* Wfc = (const float*)d_in[14];
  const float* bfc = (const float*)d_in[15];

  constexpr size_t TBUF = 2097152;  // 32768 * 64 floats
  float* wsf = (float*)d_ws;
  float* buf0 = wsf;                // also holds each layer's BN output h
  float* buf1 = buf0 + TBUF;
  float* buf2 = buf1 + TBUF;
  float* acc = buf2 + TBUF;
  float* S = acc + TBUF;                       // NSLICE partial colsums
  float* D = S + (size_t)NSLICE * ROWS;
  double* part = (double*)(D + ROWS);          // 256 * 2 * 64 doubles
  float* sc = (float*)(part + (size_t)BN_BLOCKS * 2 * 64);
  size_t need = (size_t)((sc + 128) - wsf) * sizeof(float);
  if (ws_size < need) return;  // insufficient workspace (output stays poisoned)

  float* bufs[3] = {buf0, buf1, buf2};

  // ---- Laplacian (in place over A) ----
  colsum_w<<<dim3(4, NSLICE, NB), 256, 0, stream>>>(A, x, S);
  d_kernel<<<128, 256, 0, stream>>>(S, D);
  scale_L<<<4096, 256, 0, stream>>>(A, D);

  // ---- layer 1: F=3 -> G=32, input x ----
  acc0_gemm<3, 32><<<512, 256, 0, stream>>>(x, W1, acc);
  {
    const float* Tm1 = x;
    const float* Tm2 = nullptr;
    for (int k = 1; k <= 8; ++k) {
      float* outb = bufs[k % 3];   // k=1->buf1, k=2->buf2, k=3->buf0, ...
      float alpha = (k == 1) ? 1.f : 2.f;
      float beta = (k == 1) ? 0.f : -1.f;
      cheb_l1<<<dim3(64, NB), 256, 0, stream>>>(
          A, Tm1, (k == 1) ? x : Tm2, outb, W1 + k * 3 * 32, acc, alpha, beta);
      Tm2 = Tm1;
      Tm1 = outb;
    }
  }
  bn_part<32><<<BN_BLOCKS, 256, 0, stream>>>(acc, part);
  bn_final<32><<<1, 64, 0, stream>>>(part, g1, be1, sc);
  bn_apply_elu<32><<<1024, 256, 0, stream>>>(acc, sc, buf0);  // h1 -> buf0

  // ---- layer 2: F=32 -> G=64, input buf0 ----
  acc0_gemm<32, 64><<<512, 256, 0, stream>>>(buf0, W2, acc);
  {
    const float* Tm1 = buf0;
    const float* Tm2 = nullptr;
    for (int k = 1; k <= 8; ++k) {
      float* outb = bufs[k % 3];   // k=3 overwrites buf0: h1 dead after k=2
      float alpha = (k == 1) ? 1.f : 2.f;
      float beta = (k == 1) ? 0.f : -1.f;
      cheb_gemm<128, 32, 64><<<dim3(8, NB), 256, 0, stream>>>(
          A, Tm1, (k == 1) ? buf0 : Tm2, outb, W2 + k * 32 * 64, acc, alpha,
          beta);
      Tm2 = Tm1;
      Tm1 = outb;
    }
  }
  bn_part<64><<<BN_BLOCKS, 256, 0, stream>>>(acc, part);
  bn_final<64><<<1, 64, 0, stream>>>(part, g2, be2, sc);
  bn_apply_elu<64><<<2048, 256, 0, stream>>>(acc, sc, buf0);  // h2 -> buf0

  // ---- layer 3: F=64 -> G=64, input buf0 ----
  acc0_gemm<64, 64><<<512, 256, 0, stream>>>(buf0, W3, acc);
  {
    const float* Tm1 = buf0;
    const float* Tm2 = nullptr;
    for (int k = 1; k <= 8; ++k) {
      float* outb = bufs[k % 3];
      float alpha = (k == 1) ? 1.f : 2.f;
      float beta = (k == 1) ? 0.f : -1.f;
      cheb_gemm<64, 64, 64><<<dim3(16, NB), 256, 0, stream>>>(
          A, Tm1, (k == 1) ? buf0 : Tm2, outb, W3 + k * 64 * 64, acc, alpha,
          beta);
      Tm2 = Tm1;
      Tm1 = outb;
    }
  }
  bn_part<64><<<BN_BLOCKS, 256, 0, stream>>>(acc, part);
  bn_final<64><<<1, 64, 0, stream>>>(part, g3, be3, sc);
  bn_apply_elu<64><<<2048, 256, 0, stream>>>(acc, sc, buf0);  // h3 -> buf0

  // ---- head ----
  final_k<<<NB, 256, 0, stream>>>(buf0, Wfc, bfc, (float*)d_out);
}

// Round 3
// 1596.492 us; speedup vs baseline: 1.2327x; 1.2327x over previous
//
#include <hip/hip_runtime.h>
#include <hip/hip_bf16.h>
#include <math.h>

constexpr int NN = 1024;          // nodes
constexpr int NB = 32;            // batch
constexpr int ROWS = NB * NN;     // 32768 rows for BN
constexpr int NSLICE = 8;         // colsum partial slices (deterministic)

// ---------------------------------------------------------------------------
// Laplacian: computed IN PLACE over A (harness restores inputs every launch).
// ---------------------------------------------------------------------------

__global__ __launch_bounds__(256) void colsum_w(float* __restrict__ A,
                                                const float* __restrict__ x,
                                                float* __restrict__ S) {
  const int b = blockIdx.z;
  const int j = blockIdx.x * 256 + threadIdx.x;   // column handled by thread
  const int slice = blockIdx.y;
  const int ibase = slice * 128;                  // i-slice
  __shared__ float xs[128 * 3];
  for (int idx = threadIdx.x; idx < 384; idx += 256)
    xs[idx] = x[(size_t)(b * NN + ibase) * 3 + idx];
  const float xj0 = x[(size_t)(b * NN + j) * 3 + 0];
  const float xj1 = x[(size_t)(b * NN + j) * 3 + 1];
  const float xj2 = x[(size_t)(b * NN + j) * 3 + 2];
  __syncthreads();
  float s = 0.f;
  size_t off = ((size_t)b << 20) + (size_t)ibase * NN + j;
  for (int ii = 0; ii < 128; ++ii, off += NN) {
    float a = A[off];
    float dx = xj0 - xs[ii * 3 + 0];
    float dy = xj1 - xs[ii * 3 + 1];
    float dz = xj2 - xs[ii * 3 + 2];
    float dist = sqrtf(dx * dx + dy * dy + dz * dz);
    float w = a / (dist + 0.001f);
    A[off] = w;                                   // W in place (own element)
    s += w;
  }
  S[(size_t)slice * ROWS + b * NN + j] = s;       // written exactly once
}

__global__ __launch_bounds__(256) void d_kernel(const float* __restrict__ S,
                                                float* __restrict__ D) {
  int i = blockIdx.x * 256 + threadIdx.x;
  if (i < ROWS) {
    float s = 0.f;
#pragma unroll
    for (int p = 0; p < NSLICE; ++p) s += S[(size_t)p * ROWS + i];
    D[i] = 1.f / sqrtf(s);
  }
}

__global__ __launch_bounds__(256) void scale_L(float* __restrict__ A,
                                               const float* __restrict__ D) {
  const long total4 = (long)NB * NN * NN / 4;
  for (long idx = (long)blockIdx.x * 256 + threadIdx.x; idx < total4;
       idx += (long)gridDim.x * 256) {
    long base = idx * 4;
    int j0 = (int)(base & (NN - 1));
    int i = (int)((base >> 10) & (NN - 1));
    int b = (int)(base >> 20);
    float4 w = reinterpret_cast<float4*>(A)[idx];
    float di = D[b * NN + i];
    float4 dj = *reinterpret_cast<const float4*>(&D[b * NN + j0]);
    float4 l;
    l.x = -0.5f * di * dj.x * w.x;
    l.y = -0.5f * di * dj.y * w.y;
    l.z = -0.5f * di * dj.z * w.z;
    l.w = -0.5f * di * dj.w * w.w;
    int dd = i - j0;
    if (dd == 0) l.x -= 0.5f;
    else if (dd == 1) l.y -= 0.5f;
    else if (dd == 2) l.z -= 0.5f;
    else if (dd == 3) l.w -= 0.5f;
    reinterpret_cast<float4*>(A)[idx] = l;
  }
}

// ---------------------------------------------------------------------------
// acc = h @ W0  (the k=0 term, overwrite).  RB=64 rows per block.
// ---------------------------------------------------------------------------
template <int F, int G>
__global__ __launch_bounds__(256) void acc0_gemm(const float* __restrict__ h,
                                                 const float* __restrict__ W0,
                                                 float* __restrict__ acc) {
  constexpr int RB = 64;
  constexpr int TGN = G / 16;
  __shared__ float Hs[RB][F + 1];
  __shared__ float Ws[F][G];
  const int tid = threadIdx.x;
  const size_t row0 = (size_t)blockIdx.x * RB;
  for (int idx = tid; idx < RB * F; idx += 256)
    Hs[idx / F][idx % F] = h[row0 * F + idx];
  for (int idx = tid; idx < F * G; idx += 256)
    Ws[idx / G][idx % G] = W0[idx];
  __syncthreads();
  const int tx = tid % 16, ty = tid / 16;
  float o[4][TGN];
#pragma unroll
  for (int r = 0; r < 4; ++r)
#pragma unroll
    for (int c = 0; c < TGN; ++c) o[r][c] = 0.f;
#pragma unroll 4
  for (int f = 0; f < F; ++f) {
    float a[4];
#pragma unroll
    for (int r = 0; r < 4; ++r) a[r] = Hs[ty * 4 + r][f];
#pragma unroll
    for (int c = 0; c < TGN; ++c) {
      float w = Ws[f][tx * TGN + c];
#pragma unroll
      for (int r = 0; r < 4; ++r) o[r][c] = fmaf(a[r], w, o[r][c]);
    }
  }
#pragma unroll
  for (int r = 0; r < 4; ++r) {
    size_t base = (row0 + ty * 4 + r) * G + tx * TGN;
#pragma unroll
    for (int c = 0; c < TGN; ++c) acc[base + c] = o[r][c];
  }
}

// ---------------------------------------------------------------------------
// Layer-1 recursion (F=3). Block = 256 thr (4 waves), 16 rows (4 per wave).
// ---------------------------------------------------------------------------
__global__ __launch_bounds__(256) void cheb_l1(
    const float* __restrict__ Lg, const float* __restrict__ Tprev,
    const float* __restrict__ Tpp, float* __restrict__ Tk,
    const float* __restrict__ Wk, float* __restrict__ acc, float alpha,
    float beta) {
  __shared__ float Ts[NN * 3];        // 12 KB
  __shared__ float tkv[16][4];
  const int b = blockIdx.y;
  const int i0 = blockIdx.x * 16;
  const int tid = threadIdx.x;
  const float* tpb = &Tprev[(size_t)b * NN * 3];
  for (int idx = tid; idx < 768; idx += 256)
    *reinterpret_cast<float4*>(&Ts[idx * 4]) =
        *reinterpret_cast<const float4*>(&tpb[idx * 4]);
  __syncthreads();
  const int wv = tid >> 6, ln = tid & 63;
#pragma unroll
  for (int r = 0; r < 4; ++r) {
    const int i = i0 + wv * 4 + r;
    const float* Lrow = &Lg[((size_t)b << 20) + (size_t)i * NN];
    float a0 = 0.f, a1 = 0.f, a2 = 0.f;
#pragma unroll
    for (int c = 0; c < 16; ++c) {
      int j = c * 64 + ln;
      float w = Lrow[j];
      a0 = fmaf(w, Ts[j * 3 + 0], a0);
      a1 = fmaf(w, Ts[j * 3 + 1], a1);
      a2 = fmaf(w, Ts[j * 3 + 2], a2);
    }
#pragma unroll
    for (int off = 32; off; off >>= 1) {
      a0 += __shfl_down(a0, off, 64);
      a1 += __shfl_down(a1, off, 64);
      a2 += __shfl_down(a2, off, 64);
    }
    if (ln == 0) {
      const size_t rbase = (size_t)(b * NN + i) * 3;
      float t0 = alpha * a0, t1 = alpha * a1, t2 = alpha * a2;
      if (beta != 0.f) {
        t0 = fmaf(beta, Tpp[rbase + 0], t0);
        t1 = fmaf(beta, Tpp[rbase + 1], t1);
        t2 = fmaf(beta, Tpp[rbase + 2], t2);
      }
      Tk[rbase + 0] = t0;
      Tk[rbase + 1] = t1;
      Tk[rbase + 2] = t2;
      tkv[wv * 4 + r][0] = t0;
      tkv[wv * 4 + r][1] = t1;
      tkv[wv * 4 + r][2] = t2;
    }
  }
  __syncthreads();
  for (int idx = tid; idx < 16 * 32; idx += 256) {
    int rr = idx >> 5, cc = idx & 31;
    float v = tkv[rr][0] * Wk[cc] + tkv[rr][1] * Wk[32 + cc] +
              tkv[rr][2] * Wk[64 + cc];
    acc[(size_t)(b * NN + i0 + rr) * 32 + cc] += v;
  }
}

// ---------------------------------------------------------------------------
// Split-K partial GEMM: partial[ks][rows][F] = L[:, ks-chunk] @ Tprev[ks-chunk]
// Grid: (NN/BM, NSPLIT, NB). No epilogue -> small LDS, high occupancy.
// ---------------------------------------------------------------------------
template <int BM, int F, int KS>
__global__ __launch_bounds__(256) void cheb_gemm_sk(
    const float* __restrict__ Lg, const float* __restrict__ Tprev,
    float* __restrict__ partial) {
  constexpr int BK = 32;
  constexpr int TM = 4, TN = 4;
  constexpr int NTX = F / TN;
  constexpr int NTY = BM / TM;
  static_assert(NTX * NTY == 256, "tile mismatch");

  __shared__ float As[BM][BK + 1];
  __shared__ float Bs[BK][F];

  const int tid = threadIdx.x;
  const int tx = tid % NTX, ty = tid / NTX;
  const int b = blockIdx.z;
  const int ks = blockIdx.y;
  const int i0 = blockIdx.x * BM;

  float accT[TM][TN];
#pragma unroll
  for (int r = 0; r < TM; ++r)
#pragma unroll
    for (int c = 0; c < TN; ++c) accT[r][c] = 0.f;

  const size_t Lbase = ((size_t)b << 20);
  constexpr int A_ITERS = (BM * (BK / 4)) / 256;
  constexpr int B_ITERS = (BK * (F / 4) + 255) / 256;

  const int kbeg = ks * KS, kend = kbeg + KS;
  for (int k0 = kbeg; k0 < kend; k0 += BK) {
#pragma unroll
    for (int it = 0; it < A_ITERS; ++it) {
      int idx = tid + it * 256;
      int m = idx >> 3, k4 = idx & 7;
      float4 v = *reinterpret_cast<const float4*>(
          &Lg[Lbase + (size_t)(i0 + m) * NN + k0 + k4 * 4]);
      As[m][k4 * 4 + 0] = v.x;
      As[m][k4 * 4 + 1] = v.y;
      As[m][k4 * 4 + 2] = v.z;
      As[m][k4 * 4 + 3] = v.w;
    }
#pragma unroll
    for (int it = 0; it < B_ITERS; ++it) {
      int idx = tid + it * 256;
      int kr = idx / (F / 4), c4 = idx % (F / 4);
      float4 v = *reinterpret_cast<const float4*>(
          &Tprev[(size_t)(b * NN + k0 + kr) * F + c4 * 4]);
      *reinterpret_cast<float4*>(&Bs[kr][c4 * 4]) = v;
    }
    __syncthreads();
#pragma unroll
    for (int kk = 0; kk < BK; ++kk) {
      float a[TM];
#pragma unroll
      for (int r = 0; r < TM; ++r) a[r] = As[ty * TM + r][kk];
      float4 bv = *reinterpret_cast<const float4*>(&Bs[kk][tx * TN]);
      float bb[4] = {bv.x, bv.y, bv.z, bv.w};
#pragma unroll
      for (int r = 0; r < TM; ++r)
#pragma unroll
        for (int c = 0; c < TN; ++c)
          accT[r][c] = fmaf(a[r], bb[c], accT[r][c]);
    }
    __syncthreads();
  }

#pragma unroll
  for (int r = 0; r < TM; ++r) {
    size_t gidx =
        ((size_t)ks * ROWS + (size_t)(b * NN + i0 + ty * TM + r)) * F + tx * TN;
    float4 tv = {accT[r][0], accT[r][1], accT[r][2], accT[r][3]};
    *reinterpret_cast<float4*>(&partial[gidx]) = tv;
  }
}

// ---------------------------------------------------------------------------
// Reduce NS partials -> Tk = alpha*sum + beta*Tpp ; fused acc += Tk @ Wk
// Grid: ROWS/64 blocks of 256 threads.
// ---------------------------------------------------------------------------
template <int F, int G, int NS>
__global__ __launch_bounds__(256) void cheb_reduce(
    const float* __restrict__ partial, const float* __restrict__ Tpp,
    float* __restrict__ Tk, const float* __restrict__ Wk,
    float* __restrict__ acc, float alpha, float beta) {
  constexpr int RB = 64;
  constexpr int TGN = G / 16;
  __shared__ float Ts[RB][F + 1];
  __shared__ float Ws[F][G];
  const int tid = threadIdx.x;
  const size_t row0 = (size_t)blockIdx.x * RB;

  constexpr int W_ITERS = (F * G / 4) / 256;
#pragma unroll
  for (int it = 0; it < W_ITERS; ++it) {
    int idx = tid + it * 256;
    int r = idx / (G / 4), c4 = idx % (G / 4);
    *reinterpret_cast<float4*>(&Ws[r][c4 * 4]) =
        *reinterpret_cast<const float4*>(&Wk[r * G + c4 * 4]);
  }

  const bool hasB = (beta != 0.f);
  constexpr int P_ITERS = (RB * (F / 4)) / 256;
#pragma unroll
  for (int it = 0; it < P_ITERS; ++it) {
    int idx = tid + it * 256;
    int row = idx / (F / 4), c4 = idx % (F / 4);
    size_t g = (row0 + row) * F + c4 * 4;
    float4 s = *reinterpret_cast<const float4*>(&partial[g]);
#pragma unroll
    for (int p = 1; p < NS; ++p) {
      float4 v =
          *reinterpret_cast<const float4*>(&partial[(size_t)p * ROWS * F + g]);
      s.x += v.x; s.y += v.y; s.z += v.z; s.w += v.w;
    }
    float t0 = alpha * s.x, t1 = alpha * s.y;
    float t2 = alpha * s.z, t3 = alpha * s.w;
    if (hasB) {
      float4 p = *reinterpret_cast<const float4*>(&Tpp[g]);
      t0 = fmaf(beta, p.x, t0);
      t1 = fmaf(beta, p.y, t1);
      t2 = fmaf(beta, p.z, t2);
      t3 = fmaf(beta, p.w, t3);
    }
    float4 tv = {t0, t1, t2, t3};
    *reinterpret_cast<float4*>(&Tk[g]) = tv;
    Ts[row][c4 * 4 + 0] = t0;
    Ts[row][c4 * 4 + 1] = t1;
    Ts[row][c4 * 4 + 2] = t2;
    Ts[row][c4 * 4 + 3] = t3;
  }
  __syncthreads();

  const int tx = tid % 16, ty = tid / 16;
  float o[4][TGN];
#pragma unroll
  for (int r = 0; r < 4; ++r)
#pragma unroll
    for (int c = 0; c < TGN; ++c) o[r][c] = 0.f;
#pragma unroll 8
  for (int f = 0; f < F; ++f) {
    float a[4];
#pragma unroll
    for (int r = 0; r < 4; ++r) a[r] = Ts[ty * 4 + r][f];
#pragma unroll
    for (int c = 0; c < TGN; ++c) {
      float w = Ws[f][tx * TGN + c];
#pragma unroll
      for (int r = 0; r < 4; ++r) o[r][c] = fmaf(a[r], w, o[r][c]);
    }
  }
#pragma unroll
  for (int r = 0; r < 4; ++r) {
    size_t base = (row0 + ty * 4 + r) * G + tx * TGN;
#pragma unroll
    for (int c = 0; c < TGN; ++c) acc[base + c] += o[r][c];
  }
}

// ---------------------------------------------------------------------------
// Fallback fused recursion GEMM (round-2 proven path, used if ws too small)
// ---------------------------------------------------------------------------
template <int BM, int F, int G>
__global__ __launch_bounds__(256) void cheb_gemm(
    const float* __restrict__ Lg, const float* __restrict__ Tprev,
    const float* __restrict__ Tpp, float* __restrict__ Tk,
    const float* __restrict__ Wk, float* __restrict__ acc, float alpha,
    float beta) {
  constexpr int BK = 32;
  constexpr int TM = 4, TN = 4;
  constexpr int NTX = F / TN;
  constexpr int NTY = BM / TM;
  static_assert(NTX * NTY == 256, "tile mismatch");
  constexpr int TGN = G / NTX;

  __shared__ float As[BM][BK + 1];
  __shared__ float Bs[BK][F];
  __shared__ float Ws[F][G];
  __shared__ float Ts[BM][F + 1];

  const int tid = threadIdx.x;
  const int tx = tid % NTX, ty = tid / NTX;
  const int b = blockIdx.y;
  const int i0 = blockIdx.x * BM;

  constexpr int W_ITERS = (F * G / 4) / 256;
#pragma unroll
  for (int it = 0; it < W_ITERS; ++it) {
    int idx = tid + it * 256;
    int r = idx / (G / 4), c4 = idx % (G / 4);
    float4 v = *reinterpret_cast<const float4*>(&Wk[r * G + c4 * 4]);
    *reinterpret_cast<float4*>(&Ws[r][c4 * 4]) = v;
  }

  float accT[TM][TN];
#pragma unroll
  for (int r = 0; r < TM; ++r)
#pragma unroll
    for (int c = 0; c < TN; ++c) accT[r][c] = 0.f;

  const size_t Lbase = ((size_t)b << 20);
  constexpr int A_ITERS = (BM * (BK / 4)) / 256;
  constexpr int B_ITERS = (BK * (F / 4) + 255) / 256;

  for (int k0 = 0; k0 < NN; k0 += BK) {
#pragma unroll
    for (int it = 0; it < A_ITERS; ++it) {
      int idx = tid + it * 256;
      int m = idx >> 3, k4 = idx & 7;
      float4 v = *reinterpret_cast<const float4*>(
          &Lg[Lbase + (size_t)(i0 + m) * NN + k0 + k4 * 4]);
      As[m][k4 * 4 + 0] = v.x;
      As[m][k4 * 4 + 1] = v.y;
      As[m][k4 * 4 + 2] = v.z;
      As[m][k4 * 4 + 3] = v.w;
    }
#pragma unroll
    for (int it = 0; it < B_ITERS; ++it) {
      int idx = tid + it * 256;
      int kr = idx / (F / 4), c4 = idx % (F / 4);
      float4 v = *reinterpret_cast<const float4*>(
          &Tprev[(size_t)(b * NN + k0 + kr) * F + c4 * 4]);
      *reinterpret_cast<float4*>(&Bs[kr][c4 * 4]) = v;
    }
    __syncthreads();
#pragma unroll
    for (int kk = 0; kk < BK; ++kk) {
      float a[TM];
#pragma unroll
      for (int r = 0; r < TM; ++r) a[r] = As[ty * TM + r][kk];
      float4 bv = *reinterpret_cast<const float4*>(&Bs[kk][tx * TN]);
      float bb[4] = {bv.x, bv.y, bv.z, bv.w};
#pragma unroll
      for (int r = 0; r < TM; ++r)
#pragma unroll
        for (int c = 0; c < TN; ++c)
          accT[r][c] = fmaf(a[r], bb[c], accT[r][c]);
    }
    __syncthreads();
  }

  const bool hasB = (beta != 0.f);
#pragma unroll
  for (int r = 0; r < TM; ++r) {
    int row = i0 + ty * TM + r;
    size_t gidx = (size_t)(b * NN + row) * F + tx * TN;
    float t0 = alpha * accT[r][0], t1 = alpha * accT[r][1];
    float t2 = alpha * accT[r][2], t3 = alpha * accT[r][3];
    if (hasB) {
      float4 p = *reinterpret_cast<const float4*>(&Tpp[gidx]);
      t0 = fmaf(beta, p.x, t0);
      t1 = fmaf(beta, p.y, t1);
      t2 = fmaf(beta, p.z, t2);
      t3 = fmaf(beta, p.w, t3);
    }
    float4 tv = {t0, t1, t2, t3};
    *reinterpret_cast<float4*>(&Tk[gidx]) = tv;
    Ts[ty * TM + r][tx * TN + 0] = t0;
    Ts[ty * TM + r][tx * TN + 1] = t1;
    Ts[ty * TM + r][tx * TN + 2] = t2;
    Ts[ty * TM + r][tx * TN + 3] = t3;
  }
  __syncthreads();

  float oacc[TM][TGN];
#pragma unroll
  for (int r = 0; r < TM; ++r)
#pragma unroll
    for (int c = 0; c < TGN; ++c) oacc[r][c] = 0.f;
#pragma unroll 8
  for (int f = 0; f < F; ++f) {
    float a[TM];
#pragma unroll
    for (int r = 0; r < TM; ++r) a[r] = Ts[ty * TM + r][f];
#pragma unroll
    for (int c = 0; c < TGN; ++c) {
      float w = Ws[f][tx * TGN + c];
#pragma unroll
      for (int r = 0; r < TM; ++r) oacc[r][c] = fmaf(a[r], w, oacc[r][c]);
    }
  }
#pragma unroll
  for (int r = 0; r < TM; ++r) {
    int row = i0 + ty * TM + r;
    size_t base = (size_t)(b * NN + row) * G + tx * TGN;
#pragma unroll
    for (int c = 0; c < TGN; ++c) acc[base + c] += oacc[r][c];
  }
}

// ---------------------------------------------------------------------------
// BatchNorm (train, biased var) + ELU
// ---------------------------------------------------------------------------
constexpr int BN_BLOCKS = 256;

template <int C>
__global__ __launch_bounds__(256) void bn_part(const float* __restrict__ acc,
                                               double* __restrict__ part) {
  constexpr int GR = 256 / C;
  const int tid = threadIdx.x;
  const int c = tid % C;
  const int g = tid / C;
  double s = 0.0, s2 = 0.0;
  for (int r = blockIdx.x * GR + g; r < ROWS; r += BN_BLOCKS * GR) {
    double v = (double)acc[(size_t)r * C + c];
    s += v;
    s2 += v * v;
  }
  __shared__ double Ls[256], Ls2[256];
  Ls[tid] = s;
  Ls2[tid] = s2;
  __syncthreads();
  for (int str = 128; str >= C; str >>= 1) {
    if (tid < str) {
      Ls[tid] += Ls[tid + str];
      Ls2[tid] += Ls2[tid + str];
    }
    __syncthreads();
  }
  if (tid < C) {
    part[(size_t)blockIdx.x * 2 * C + tid] = Ls[tid];
    part[(size_t)blockIdx.x * 2 * C + C + tid] = Ls2[tid];
  }
}

template <int C>
__global__ void bn_final(const double* __restrict__ part,
                         const float* __restrict__ g,
                         const float* __restrict__ be,
                         float* __restrict__ sc) {
  int t = threadIdx.x;
  if (t < C) {
    double s = 0.0, s2 = 0.0;
    for (int b = 0; b < BN_BLOCKS; ++b) {
      s += part[(size_t)b * 2 * C + t];
      s2 += part[(size_t)b * 2 * C + C + t];
    }
    double mu = s / ROWS;
    double var = s2 / ROWS - mu * mu;
    float scale = g[t] / sqrtf((float)var + 1e-5f);
    sc[t] = scale;
    sc[C + t] = be[t] - (float)mu * scale;
  }
}

template <int C>
__global__ __launch_bounds__(256) void bn_apply_elu(
    const float* __restrict__ acc, const float* __restrict__ sc,
    float* __restrict__ h) {
  const long total4 = (long)ROWS * C / 4;
  for (long idx = (long)blockIdx.x * 256 + threadIdx.x; idx < total4;
       idx += (long)gridDim.x * 256) {
    long base = idx * 4;
    int c0 = (int)(base % C);
    float4 v = reinterpret_cast<const float4*>(acc)[idx];
    float t0 = fmaf(v.x, sc[c0 + 0], sc[C + c0 + 0]);
    float t1 = fmaf(v.y, sc[c0 + 1], sc[C + c0 + 1]);
    float t2 = fmaf(v.z, sc[c0 + 2], sc[C + c0 + 2]);
    float t3 = fmaf(v.w, sc[c0 + 3], sc[C + c0 + 3]);
    float4 o;
    o.x = t0 > 0.f ? t0 : expm1f(t0);
    o.y = t1 > 0.f ? t1 : expm1f(t1);
    o.z = t2 > 0.f ? t2 : expm1f(t2);
    o.w = t3 > 0.f ? t3 : expm1f(t3);
    reinterpret_cast<float4*>(h)[idx] = o;
  }
}

// ---------------------------------------------------------------------------
// Final: mean over nodes, dot with Wfc, + bfc
// ---------------------------------------------------------------------------
__global__ __launch_bounds__(256) void final_k(const float* __restrict__ h,
                                               const float* __restrict__ Wfc,
                                               const float* __restrict__ bfc,
                                               float* __restrict__ out) {
  const int b = blockIdx.x;
  const int tid = threadIdx.x;
  const int c = tid % 64;
  const int g = tid / 64;
  float s = 0.f;
  for (int r = g; r < NN; r += 4) s += h[(size_t)(b * NN + r) * 64 + c];
  __shared__ float red[256];
  red[tid] = s;
  __syncthreads();
  if (tid < 128) red[tid] += red[tid + 128];
  __syncthreads();
  if (tid < 64) {
    float pooled = (red[tid] + red[tid + 64]) * (1.0f / 1024.0f);
    float v = pooled * Wfc[tid];
#pragma unroll
    for (int off = 32; off; off >>= 1) v += __shfl_down(v, off, 64);
    if (tid == 0) out[b] = v + bfc[0];
  }
}

// ---------------------------------------------------------------------------
extern "C" void kernel_launch(void* const* d_in, const int* in_sizes, int n_in,
                              void* d_out, int out_size, void* d_ws,
                              size_t ws_size, hipStream_t stream) {
  const float* x = (const float*)d_in[0];
  float* A = (float*)d_in[1];  // overwritten in place with L
  const float* W1 = (const float*)d_in[2];
  const float* g1 = (const float*)d_in[4];
  const float* be1 = (const float*)d_in[5];
  const float* W2 = (const float*)d_in[6];
  const float* g2 = (const float*)d_in[8];
  const float* be2 = (const float*)d_in[9];
  const float* W3 = (const float*)d_in[10];
  const float* g3 = (const float*)d_in[12];
  const float* be3 = (const float*)d_in[13];
  const float* Wfc = (const float*)d_in[14];
  const float* bfc = (const float*)d_in[15];

  constexpr size_t TBUF = 2097152;            // 32768 * 64 floats
  constexpr size_t PARTIAL_F = 4194304;       // 4*ROWS*32 == 2*ROWS*64 floats
  float* wsf = (float*)d_ws;
  float* buf0 = wsf;                // also holds each layer's BN output h
  float* buf1 = buf0 + TBUF;
  float* buf2 = buf1 + TBUF;
  float* acc = buf2 + TBUF;
  float* R = acc + TBUF;            // overlay region: S/D (laplacian) | partial
  float* S = R;                     // NSLICE * ROWS floats
  float* D = S + (size_t)NSLICE * ROWS;
  float* partial = R;               // PARTIAL_F floats (after laplacian done)

  // split-K layout: part/sc after partial region
  double* part_sk = (double*)(R + PARTIAL_F);
  float* sc_sk = (float*)(part_sk + (size_t)BN_BLOCKS * 2 * 64);
  size_t need_sk = (size_t)((sc_sk + 128) - wsf) * sizeof(float);
  // fallback layout: part/sc right after S/D (round-2 proven footprint)
  double* part_fb = (double*)(D + ROWS);
  float* sc_fb = (float*)(part_fb + (size_t)BN_BLOCKS * 2 * 64);
  size_t need_fb = (size_t)((sc_fb + 128) - wsf) * sizeof(float);

  const bool use_sk = (ws_size >= need_sk);
  if (!use_sk && ws_size < need_fb) return;  // insufficient workspace
  double* part = use_sk ? part_sk : part_fb;
  float* sc = use_sk ? sc_sk : sc_fb;

  float* bufs[3] = {buf0, buf1, buf2};

  // ---- Laplacian (in place over A) ----
  colsum_w<<<dim3(4, NSLICE, NB), 256, 0, stream>>>(A, x, S);
  d_kernel<<<128, 256, 0, stream>>>(S, D);
  scale_L<<<4096, 256, 0, stream>>>(A, D);

  // ---- layer 1: F=3 -> G=32, input x ----
  acc0_gemm<3, 32><<<512, 256, 0, stream>>>(x, W1, acc);
  {
    const float* Tm1 = x;
    const float* Tm2 = nullptr;
    for (int k = 1; k <= 8; ++k) {
      float* outb = bufs[k % 3];
      float alpha = (k == 1) ? 1.f : 2.f;
      float beta = (k == 1) ? 0.f : -1.f;
      cheb_l1<<<dim3(64, NB), 256, 0, stream>>>(
          A, Tm1, (k == 1) ? x : Tm2, outb, W1 + k * 3 * 32, acc, alpha, beta);
      Tm2 = Tm1;
      Tm1 = outb;
    }
  }
  bn_part<32><<<BN_BLOCKS, 256, 0, stream>>>(acc, part);
  bn_final<32><<<1, 64, 0, stream>>>(part, g1, be1, sc);
  bn_apply_elu<32><<<1024, 256, 0, stream>>>(acc, sc, buf0);  // h1 -> buf0

  // ---- layer 2: F=32 -> G=64, input buf0 ----
  acc0_gemm<32, 64><<<512, 256, 0, stream>>>(buf0, W2, acc);
  {
    const float* Tm1 = buf0;
    const float* Tm2 = nullptr;
    for (int k = 1; k <= 8; ++k) {
      float* outb = bufs[k % 3];   // k=3 overwrites buf0: h1 dead after k=2
      float alpha = (k == 1) ? 1.f : 2.f;
      float beta = (k == 1) ? 0.f : -1.f;
      const float* tpp = (k == 1) ? buf0 : Tm2;
      if (use_sk) {
        cheb_gemm_sk<128, 32, 256><<<dim3(8, 4, NB), 256, 0, stream>>>(
            A, Tm1, partial);
        cheb_reduce<32, 64, 4><<<ROWS / 64, 256, 0, stream>>>(
            partial, tpp, outb, W2 + k * 32 * 64, acc, alpha, beta);
      } else {
        cheb_gemm<128, 32, 64><<<dim3(8, NB), 256, 0, stream>>>(
            A, Tm1, tpp, outb, W2 + k * 32 * 64, acc, alpha, beta);
      }
      Tm2 = Tm1;
      Tm1 = outb;
    }
  }
  bn_part<64><<<BN_BLOCKS, 256, 0, stream>>>(acc, part);
  bn_final<64><<<1, 64, 0, stream>>>(part, g2, be2, sc);
  bn_apply_elu<64><<<2048, 256, 0, stream>>>(acc, sc, buf0);  // h2 -> buf0

  // ---- layer 3: F=64 -> G=64, input buf0 ----
  acc0_gemm<64, 64><<<512, 256, 0, stream>>>(buf0, W3, acc);
  {
    const float* Tm1 = buf0;
    const float* Tm2 = nullptr;
    for (int k = 1; k <= 8; ++k) {
      float* outb = bufs[k % 3];
      float alpha = (k == 1) ? 1.f : 2.f;
      float beta = (k == 1) ? 0.f : -1.f;
      const float* tpp = (k == 1) ? buf0 : Tm2;
      if (use_sk) {
        cheb_gemm_sk<64, 64, 512><<<dim3(16, 2, NB), 256, 0, stream>>>(
            A, Tm1, partial);
        cheb_reduce<64, 64, 2><<<ROWS / 64, 256, 0, stream>>>(
            partial, tpp, outb, W3 + k * 64 * 64, acc, alpha, beta);
      } else {
        cheb_gemm<64, 64, 64><<<dim3(16, NB), 256, 0, stream>>>(
            A, Tm1, tpp, outb, W3 + k * 64 * 64, acc, alpha, beta);
      }
      Tm2 = Tm1;
      Tm1 = outb;
    }
  }
  bn_part<64><<<BN_BLOCKS, 256, 0, stream>>>(acc, part);
  bn_final<64><<<1, 64, 0, stream>>>(part, g3, be3, sc);
  bn_apply_elu<64><<<2048, 256, 0, stream>>>(acc, sc, buf0);  // h3 -> buf0

  // ---- head ----
  final_k<<<NB, 256, 0, stream>>>(buf0, Wfc, bfc, (float*)d_out);
}